// Round 8
// baseline (764.390 us; speedup 1.0000x reference)
//
#include <hip/hip_runtime.h>

typedef unsigned short ushort_t;
typedef unsigned int uint_t;
typedef __attribute__((ext_vector_type(8))) short bf16x8;
typedef __attribute__((ext_vector_type(4))) float f32x4;

#define C_DIM 64
#define P_DIM 1296
#define N_DIM 2000
#define B_DIM 256
#define K_DIM (C_DIM * P_DIM)               // 82944
#define XB_ELEMS (B_DIM * K_DIM)            // 21233664
#define XB_ELEMS_PAD (XB_ELEMS + 256)       // 21233920
#define XB_BYTES ((size_t)XB_ELEMS_PAD * 2) // 42467840
#define SLICES 32
#define OUT_ELEMS (B_DIM * N_DIM)           // 512000
#define NSTEP 82                            // 2 channels x 41 BK=32 steps
#define DIAG_REPS 3  // DIAGNOSTIC: repeat GEMM body to surface rocprof counters

static __device__ __forceinline__ ushort_t f2bf(float f) {
  unsigned u = __builtin_bit_cast(unsigned, f);
  u += 0x7fffu + ((u >> 16) & 1u);
  return (ushort_t)(u >> 16);
}

// ---------------- x (fp32) -> Xb (bf16) with zeroed pad tail ----------------
__global__ void klindt_cvt_kernel(const float4* __restrict__ x,
                                  unsigned long long* __restrict__ xb) {
  int idx = blockIdx.x * 256 + threadIdx.x;
  if (idx >= XB_ELEMS_PAD / 4) return;
  unsigned long long r = 0ull;
  if (idx < XB_ELEMS / 4) {
    float4 v = x[idx];
    r = (unsigned long long)f2bf(v.x) | ((unsigned long long)f2bf(v.y) << 16) |
        ((unsigned long long)f2bf(v.z) << 32) |
        ((unsigned long long)f2bf(v.w) << 48);
  }
  xb[idx] = r;
}

// ---------------- main GEMM (R6 config, DIAGNOSTIC 3x rep) ----------------
// BM=256, BN=128, BK=32, 8 waves (4Mx2N), XCD-pinned slices, vmcnt(8).
// Each rep recomputes the identical partials and stores them (keeps all reps
// live vs DCE, output unchanged, deterministic). REMOVE rep loop after diag.
__global__ void __launch_bounds__(512, 4) klindt_gemm_kernel(
    const char* __restrict__ xbb, const char* __restrict__ mwb,
    const float* __restrict__ rw, float* __restrict__ partials) {
  __shared__ ushort_t sA[2][8192];  // [256 m][32 k] bf16, 64B rows, XOR-swz
  __shared__ ushort_t sB[2][4096];  // [128 n][32 k] bf16, 64B rows, XOR-swz

  const int tid = threadIdx.x;
  const int lane = tid & 63;
  const int wid = tid >> 6;
  const int wm = wid >> 1;
  const int wn = wid & 1;
  const int bid = blockIdx.x;
  const int slice = (bid & 7) + 8 * ((bid >> 3) & 3);  // 0..31, XCD-pinned
  const int n0 = (bid >> 5) * 128;                     // 16 n-tiles
  const int c0 = slice * 2;

  // ---- A staging: linear LDS dest, inverse-swizzled global src (rule #21) --
  uint_t a_gbase[2]; int a_doff[2];
#pragma unroll
  for (int it = 0; it < 2; ++it) {
    int chunk = it * 512 + tid;
    int row = chunk >> 2, t4 = chunk & 3;
    int ss = t4 ^ ((row >> 1) & 3);
    a_gbase[it] = (uint_t)(row * K_DIM + ss * 8) * 2u;  // byte off into xb
    a_doff[it] = chunk * 8;                             // elem off into sA
  }
  // ---- B staging constants (addresses clamped; OOB-n zeroed via rv=0) ----
  uint_t b_goff[2]; int b_eoff[2], b_kj[2];
  float rvl[2], rvh[2];
#pragma unroll
  for (int it = 0; it < 2; ++it) {
    int idx = it * 512 + tid;
    int nl = idx & 15, kq = (idx >> 4) & 7, nh = idx >> 7;
    int n = nh * 16 + nl;
    int ng = n0 + n;
    int ngc = ng < (N_DIM - 1) ? ng : (N_DIM - 1);  // clamp addr
    bool okn = ng < N_DIM;
    b_kj[it] = kq * 4;
    b_goff[it] = (uint_t)kq * 2048000u + (uint_t)ngc * 4u;  // byte off into mw
    int slotp = (kq >> 1) ^ ((nl >> 1) & 3);
    b_eoff[it] = n * 32 + slotp * 8 + (kq & 1) * 4;         // elem off into sB
    rvl[it] = okn ? rw[c0 * N_DIM + ng] : 0.f;
    rvh[it] = okn ? rw[(c0 + 1) * N_DIM + ng] : 0.f;
  }

  // ---- fragment read offsets (swizzle-consistent) ----
  const int r15 = lane & 15, g4 = lane >> 4;
  const int swz = g4 ^ ((r15 >> 1) & 3);
  const int aoffbase = (wm * 64 + r15) * 32 + swz * 8;
  const int boffbase = (wn * 64 + r15) * 32 + swz * 8;

  f32x4 acc[4][4];
  float mvE[2][4], mvO[2][4];  // B register double-buffer (static parity)

  auto issueA = [&](int buf, int t) {
    int half = (t >= 41) ? 1 : 0;
    int sp = t - 41 * half;
    uint_t kb = ((uint_t)(c0 + half) * (uint_t)P_DIM + (uint_t)sp * 32u) * 2u;
#pragma unroll
    for (int it = 0; it < 2; ++it) {
      const char* g = xbb + (a_gbase[it] + kb);
      __builtin_amdgcn_global_load_lds(
          (const __attribute__((address_space(1))) unsigned int*)g,
          (__attribute__((address_space(3))) unsigned int*)(&sA[buf][a_doff[it]]),
          16, 0, 0);
    }
  };
  auto computeStep = [&](int buf) {
    bf16x8 bfr[4];
#pragma unroll
    for (int fn = 0; fn < 4; ++fn)
      bfr[fn] = *(const bf16x8*)(&sB[buf][boffbase + fn * 512]);
    __builtin_amdgcn_s_setprio(1);
#pragma unroll
    for (int fm = 0; fm < 4; ++fm) {
      bf16x8 afr = *(const bf16x8*)(&sA[buf][aoffbase + fm * 512]);
#pragma unroll
      for (int fn = 0; fn < 4; ++fn)
        acc[fm][fn] = __builtin_amdgcn_mfma_f32_16x16x32_bf16(
            afr, bfr[fn], acc[fm][fn], 0, 0, 0);
    }
    __builtin_amdgcn_s_setprio(0);
  };

#define ISSUE_B(MV, T)                                                        \
  do {                                                                        \
    int half_ = ((T) >= 41) ? 1 : 0;                                          \
    int sp_ = (T)-41 * half_;                                                 \
    uint_t ub_ = (uint_t)sp_ * 16384000u + (uint_t)(c0 + half_) * 8000u;      \
    if (sp_ < 40) { /* uniform: all p in range, no per-elem select */         \
      _Pragma("unroll") for (int it_ = 0; it_ < 2; ++it_) {                   \
        const char* bp_ = mwb + (ub_ + b_goff[it_]);                          \
        _Pragma("unroll") for (int j_ = 0; j_ < 4; ++j_)                      \
          MV[it_][j_] = *(const float*)(bp_ + (uint_t)j_ * 512000u);          \
      }                                                                       \
    } else { /* sp==40: only first 16 k valid */                              \
      _Pragma("unroll") for (int it_ = 0; it_ < 2; ++it_) {                   \
        const char* bp_ = mwb + (ub_ + b_goff[it_]);                          \
        _Pragma("unroll") for (int j_ = 0; j_ < 4; ++j_) {                    \
          bool ok_ = (b_kj[it_] + j_) < 16;                                   \
          MV[it_][j_] = ok_ ? *(const float*)(bp_ + (uint_t)j_ * 512000u)     \
                            : 0.f;                                            \
        }                                                                     \
      }                                                                       \
    }                                                                         \
  } while (0)

#define WRITE_B(BUF, MV, T)                                                   \
  do {                                                                        \
    bool hi_ = ((T) >= 41);                                                   \
    _Pragma("unroll") for (int it_ = 0; it_ < 2; ++it_) {                     \
      float r_ = hi_ ? rvh[it_] : rvl[it_];                                   \
      unsigned long long pk_ = 0ull;                                          \
      _Pragma("unroll") for (int j_ = 0; j_ < 4; ++j_)                        \
        pk_ |= (unsigned long long)f2bf(MV[it_][j_] * r_) << (16 * j_);       \
      *(unsigned long long*)(&sB[BUF][b_eoff[it_]]) = pk_;                    \
    }                                                                         \
  } while (0)

#define BODY(S, MV_ISSUE, MV_WRITE)                                           \
  {                                                                           \
    issueA(((S) + 1) & 1, (S) + 1);                                           \
    ISSUE_B(MV_ISSUE, (S) + 2);                                               \
    computeStep((S)&1);                                                       \
    WRITE_B(((S) + 1) & 1, MV_WRITE, (S) + 1);                                \
    asm volatile("s_waitcnt vmcnt(8) lgkmcnt(0)" ::: "memory");               \
    __builtin_amdgcn_sched_barrier(0);                                        \
    __builtin_amdgcn_s_barrier();                                             \
    __builtin_amdgcn_sched_barrier(0);                                        \
  }

  for (int rep = 0; rep < DIAG_REPS; ++rep) {
#pragma unroll
    for (int i = 0; i < 4; ++i)
#pragma unroll
      for (int j = 0; j < 4; ++j) {
        acc[i][j][0] = 0.f; acc[i][j][1] = 0.f;
        acc[i][j][2] = 0.f; acc[i][j][3] = 0.f;
      }

    // ---- prologue ----
    ISSUE_B(mvE, 0);
    issueA(0, 0);
    WRITE_B(0, mvE, 0);  // implicit wait drains B(0); A(0) stays in flight
    ISSUE_B(mvO, 1);
    asm volatile("s_waitcnt vmcnt(8) lgkmcnt(0)" ::: "memory");
    __builtin_amdgcn_sched_barrier(0);
    __builtin_amdgcn_s_barrier();
    __builtin_amdgcn_sched_barrier(0);

    // ---- main loop: steps 0..79 ----
    for (int s = 0; s < 80; s += 2) {
      BODY(s, mvE, mvO);
      BODY(s + 1, mvO, mvE);
    }
    // ---- peel s=80 (no B prefetch; full drain so A(81) is guaranteed) ----
    issueA(1, 81);
    computeStep(0);
    WRITE_B(1, mvO, 81);
    asm volatile("s_waitcnt vmcnt(0) lgkmcnt(0)" ::: "memory");
    __builtin_amdgcn_sched_barrier(0);
    __builtin_amdgcn_s_barrier();
    __builtin_amdgcn_sched_barrier(0);
    // ---- s=81 ----
    computeStep(1);

    // ---- epilogue per rep (keeps every rep live; identical values) ----
    float* pb = partials + (size_t)slice * OUT_ELEMS;
#pragma unroll
    for (int fm = 0; fm < 4; ++fm) {
#pragma unroll
      for (int fn = 0; fn < 4; ++fn) {
        int nn = n0 + wn * 64 + fn * 16 + r15;
        if (nn < N_DIM) {
#pragma unroll
          for (int rr = 0; rr < 4; ++rr) {
            int m = wm * 64 + fm * 16 + g4 * 4 + rr;
            pb[m * N_DIM + nn] = acc[fm][fn][rr];
          }
        }
      }
    }
    __syncthreads();  // all reads/writes of this rep done before next rep
  }
#undef BODY
#undef ISSUE_B
#undef WRITE_B
}

// ---------------- deterministic split-K reduction ----------------
__global__ void klindt_reduce_kernel(const float* __restrict__ part,
                                     float* __restrict__ out) {
  int i = blockIdx.x * 256 + threadIdx.x;
  if (i < OUT_ELEMS) {
    float s = 0.f;
#pragma unroll
    for (int k = 0; k < SLICES; ++k) s += part[(size_t)k * OUT_ELEMS + i];
    out[i] = s;
  }
}

extern "C" void kernel_launch(void* const* d_in, const int* in_sizes, int n_in,
                              void* d_out, int out_size, void* d_ws,
                              size_t ws_size, hipStream_t stream) {
  (void)in_sizes; (void)n_in; (void)out_size; (void)ws_size;
  const float* x = (const float*)d_in[0];
  const char* mwb = (const char*)d_in[1];
  const float* rw = (const float*)d_in[2];
  float* out = (float*)d_out;

  char* xbb = (char*)d_ws;
  float* partials = (float*)((char*)d_ws + XB_BYTES);

  {
    int nvec = XB_ELEMS_PAD / 4;
    int grid = (nvec + 255) / 256;
    klindt_cvt_kernel<<<grid, 256, 0, stream>>>((const float4*)x,
                                                (unsigned long long*)xbb);
  }
  {
    klindt_gemm_kernel<<<512, 512, 0, stream>>>(xbb, mwb, rw, partials);
  }
  {
    int grid = (OUT_ELEMS + 255) / 256;
    klindt_reduce_kernel<<<grid, 256, 0, stream>>>(partials, out);
  }
}

// Round 9
// 299.199 us; speedup vs baseline: 2.5548x; 2.5548x over previous
//
#include <hip/hip_runtime.h>

typedef unsigned short ushort_t;
typedef unsigned int uint_t;
typedef __attribute__((ext_vector_type(8))) short bf16x8;
typedef __attribute__((ext_vector_type(4))) float f32x4;

#define C_DIM 64
#define P_DIM 1296
#define N_DIM 2000
#define B_DIM 256
#define K_DIM (C_DIM * P_DIM)               // 82944
#define XB_ELEMS (B_DIM * K_DIM)            // 21233664
#define XB_ELEMS_PAD (XB_ELEMS + 256)       // 21233920
#define XB_BYTES ((size_t)XB_ELEMS_PAD * 2) // 42467840
#define SLICES 32
#define OUT_ELEMS (B_DIM * N_DIM)           // 512000
#define NSTEP 82                            // 2 channels x 41 BK=32 steps

static __device__ __forceinline__ ushort_t f2bf(float f) {
  unsigned u = __builtin_bit_cast(unsigned, f);
  u += 0x7fffu + ((u >> 16) & 1u);
  return (ushort_t)(u >> 16);
}

// ---------------- x (fp32) -> Xb (bf16) with zeroed pad tail ----------------
__global__ void klindt_cvt_kernel(const float4* __restrict__ x,
                                  unsigned long long* __restrict__ xb) {
  int idx = blockIdx.x * 256 + threadIdx.x;
  if (idx >= XB_ELEMS_PAD / 4) return;
  unsigned long long r = 0ull;
  if (idx < XB_ELEMS / 4) {
    float4 v = x[idx];
    r = (unsigned long long)f2bf(v.x) | ((unsigned long long)f2bf(v.y) << 16) |
        ((unsigned long long)f2bf(v.z) << 32) |
        ((unsigned long long)f2bf(v.w) << 48);
  }
  xb[idx] = r;
}

// ---------------- main GEMM: partials[slice][b][n] ----------------
// R8 diagnosis: latency/occupancy-bound (Occ 45.7%, hbm 28%, MfmaUtil 15%) —
// grid was 512 = 2 blocks/CU. Fix: BN 128->64, 32 n-tiles, grid 1024 =
// 4 blocks/CU (LDS 40KB/block = exactly 4/CU; VGPR drops with acc[4][2]).
// BM=256 keeps mw read-once; A (xb) re-reads stay XCD-L2-pinned (H9).
// 8 waves (4M x 2N), wave tile 64x32, 8 MFMA/step/wave.
__global__ void __launch_bounds__(512, 4) klindt_gemm_kernel(
    const char* __restrict__ xbb, const char* __restrict__ mwb,
    const float* __restrict__ rw, float* __restrict__ partials) {
  __shared__ ushort_t sA[2][8192];  // [256 m][32 k] bf16, 64B rows, XOR-swz
  __shared__ ushort_t sB[2][2048];  // [ 64 n][32 k] bf16, 64B rows, XOR-swz

  const int tid = threadIdx.x;
  const int lane = tid & 63;
  const int wid = tid >> 6;
  const int wm = wid >> 1;  // 0..3
  const int wn = wid & 1;   // 0..1
  const int bid = blockIdx.x;
  const int slice = (bid & 7) + 8 * ((bid >> 3) & 3);  // 0..31, XCD-pinned
  const int n0 = (bid >> 5) * 64;                      // 32 n-tiles
  const int c0 = slice * 2;

  f32x4 acc[4][2];
#pragma unroll
  for (int i = 0; i < 4; ++i)
#pragma unroll
    for (int j = 0; j < 2; ++j) {
      acc[i][j][0] = 0.f; acc[i][j][1] = 0.f;
      acc[i][j][2] = 0.f; acc[i][j][3] = 0.f;
    }

  // ---- A staging: linear LDS dest, inverse-swizzled global src (rule #21) --
  uint_t a_gbase[2]; int a_doff[2];
#pragma unroll
  for (int it = 0; it < 2; ++it) {
    int chunk = it * 512 + tid;
    int row = chunk >> 2, t4 = chunk & 3;
    int ss = t4 ^ ((row >> 1) & 3);
    a_gbase[it] = (uint_t)(row * K_DIM + ss * 8) * 2u;  // byte off into xb
    a_doff[it] = chunk * 8;                             // elem off into sA
  }
  // ---- B staging: one (n, p-quad) per thread, 4 dword loads ----
  const int nl = tid & 15, kq = (tid >> 4) & 7, nh = tid >> 7;  // nh 0..3
  const int bn = nh * 16 + nl;                                  // n 0..63
  const int b_kj = kq * 4;
  uint_t b_goff; float rvl, rvh;
  {
    int ng = n0 + bn;
    int ngc = ng < (N_DIM - 1) ? ng : (N_DIM - 1);  // clamp addr
    bool okn = ng < N_DIM;
    b_goff = (uint_t)kq * 2048000u + (uint_t)ngc * 4u;  // byte off into mw
    rvl = okn ? rw[c0 * N_DIM + ng] : 0.f;
    rvh = okn ? rw[(c0 + 1) * N_DIM + ng] : 0.f;
  }
  // sB slot-XOR identical to read side: slot(n,ks) = ks ^ ((n>>1)&3)
  const int b_eoff = bn * 32 + (((kq >> 1) ^ ((nl >> 1) & 3)) * 8) + (kq & 1) * 4;

  // ---- fragment read offsets (swizzle-consistent) ----
  const int r15 = lane & 15, g4 = lane >> 4;
  const int swz = g4 ^ ((r15 >> 1) & 3);
  const int aoffbase = (wm * 64 + r15) * 32 + swz * 8;
  const int boffbase = (wn * 32 + r15) * 32 + swz * 8;

  float mvE[4], mvO[4];  // B register double-buffer (static parity)

  auto issueA = [&](int buf, int t) {
    int half = (t >= 41) ? 1 : 0;
    int sp = t - 41 * half;
    uint_t kb = ((uint_t)(c0 + half) * (uint_t)P_DIM + (uint_t)sp * 32u) * 2u;
#pragma unroll
    for (int it = 0; it < 2; ++it) {
      const char* g = xbb + (a_gbase[it] + kb);
      __builtin_amdgcn_global_load_lds(
          (const __attribute__((address_space(1))) unsigned int*)g,
          (__attribute__((address_space(3))) unsigned int*)(&sA[buf][a_doff[it]]),
          16, 0, 0);
    }
  };
  auto computeStep = [&](int buf) {
    bf16x8 bfr[2];
#pragma unroll
    for (int fn = 0; fn < 2; ++fn)
      bfr[fn] = *(const bf16x8*)(&sB[buf][boffbase + fn * 512]);
    __builtin_amdgcn_s_setprio(1);
#pragma unroll
    for (int fm = 0; fm < 4; ++fm) {
      bf16x8 afr = *(const bf16x8*)(&sA[buf][aoffbase + fm * 512]);
#pragma unroll
      for (int fn = 0; fn < 2; ++fn)
        acc[fm][fn] = __builtin_amdgcn_mfma_f32_16x16x32_bf16(
            afr, bfr[fn], acc[fm][fn], 0, 0, 0);
    }
    __builtin_amdgcn_s_setprio(0);
  };

#define ISSUE_B(MV, T)                                                        \
  do {                                                                        \
    int half_ = ((T) >= 41) ? 1 : 0;                                          \
    int sp_ = (T)-41 * half_;                                                 \
    uint_t ub_ = (uint_t)sp_ * 16384000u + (uint_t)(c0 + half_) * 8000u;      \
    const char* bp_ = mwb + (ub_ + b_goff);                                   \
    if (sp_ < 40) { /* uniform: all p in range */                             \
      _Pragma("unroll") for (int j_ = 0; j_ < 4; ++j_)                        \
        MV[j_] = *(const float*)(bp_ + (uint_t)j_ * 512000u);                 \
    } else { /* sp==40: only first 16 k valid */                              \
      _Pragma("unroll") for (int j_ = 0; j_ < 4; ++j_) {                      \
        bool ok_ = (b_kj + j_) < 16;                                          \
        MV[j_] = ok_ ? *(const float*)(bp_ + (uint_t)j_ * 512000u) : 0.f;     \
      }                                                                       \
    }                                                                         \
  } while (0)

#define WRITE_B(BUF, MV, T)                                                   \
  do {                                                                        \
    float r_ = ((T) >= 41) ? rvh : rvl;                                       \
    unsigned long long pk_ = 0ull;                                            \
    _Pragma("unroll") for (int j_ = 0; j_ < 4; ++j_)                          \
      pk_ |= (unsigned long long)f2bf(MV[j_] * r_) << (16 * j_);              \
    *(unsigned long long*)(&sB[BUF][b_eoff]) = pk_;                           \
  } while (0)

  // ---- prologue ----
  ISSUE_B(mvE, 0);
  issueA(0, 0);
  WRITE_B(0, mvE, 0);  // implicit wait drains B(0); A(0) stays in flight
  ISSUE_B(mvO, 1);
  asm volatile("s_waitcnt vmcnt(4) lgkmcnt(0)" ::: "memory");
  __builtin_amdgcn_sched_barrier(0);
  __builtin_amdgcn_s_barrier();
  __builtin_amdgcn_sched_barrier(0);

#define BODY(S, MV_ISSUE, MV_WRITE)                                           \
  {                                                                           \
    issueA(((S) + 1) & 1, (S) + 1);                                           \
    ISSUE_B(MV_ISSUE, (S) + 2);                                               \
    computeStep((S)&1);                                                       \
    WRITE_B(((S) + 1) & 1, MV_WRITE, (S) + 1);                                \
    asm volatile("s_waitcnt vmcnt(4) lgkmcnt(0)" ::: "memory");               \
    __builtin_amdgcn_sched_barrier(0);                                        \
    __builtin_amdgcn_s_barrier();                                             \
    __builtin_amdgcn_sched_barrier(0);                                        \
  }

  // ---- main loop: steps 0..79 ----
  for (int s = 0; s < 80; s += 2) {
    BODY(s, mvE, mvO);
    BODY(s + 1, mvO, mvE);
  }
  // ---- peel s=80 (no B prefetch; full drain so A(81) is guaranteed) ----
  issueA(1, 81);
  computeStep(0);
  WRITE_B(1, mvO, 81);
  asm volatile("s_waitcnt vmcnt(0) lgkmcnt(0)" ::: "memory");
  __builtin_amdgcn_sched_barrier(0);
  __builtin_amdgcn_s_barrier();
  __builtin_amdgcn_sched_barrier(0);
  // ---- s=81 ----
  computeStep(1);

  // ---- epilogue: fp32 partials for this K-slice ----
  float* pb = partials + (size_t)slice * OUT_ELEMS;
#pragma unroll
  for (int fm = 0; fm < 4; ++fm) {
#pragma unroll
    for (int fn = 0; fn < 2; ++fn) {
      int nn = n0 + wn * 32 + fn * 16 + r15;
      if (nn < N_DIM) {
#pragma unroll
        for (int rr = 0; rr < 4; ++rr) {
          int m = wm * 64 + fm * 16 + g4 * 4 + rr;
          pb[m * N_DIM + nn] = acc[fm][fn][rr];
        }
      }
    }
  }
#undef BODY
#undef ISSUE_B
#undef WRITE_B
}

// ---------------- deterministic split-K reduction ----------------
__global__ void klindt_reduce_kernel(const float* __restrict__ part,
                                     float* __restrict__ out) {
  int i = blockIdx.x * 256 + threadIdx.x;
  if (i < OUT_ELEMS) {
    float s = 0.f;
#pragma unroll
    for (int k = 0; k < SLICES; ++k) s += part[(size_t)k * OUT_ELEMS + i];
    out[i] = s;
  }
}

extern "C" void kernel_launch(void* const* d_in, const int* in_sizes, int n_in,
                              void* d_out, int out_size, void* d_ws,
                              size_t ws_size, hipStream_t stream) {
  (void)in_sizes; (void)n_in; (void)out_size; (void)ws_size;
  const float* x = (const float*)d_in[0];
  const char* mwb = (const char*)d_in[1];
  const float* rw = (const float*)d_in[2];
  float* out = (float*)d_out;

  char* xbb = (char*)d_ws;
  float* partials = (float*)((char*)d_ws + XB_BYTES);

  {
    int nvec = XB_ELEMS_PAD / 4;
    int grid = (nvec + 255) / 256;
    klindt_cvt_kernel<<<grid, 256, 0, stream>>>((const float4*)x,
                                                (unsigned long long*)xbb);
  }
  {
    klindt_gemm_kernel<<<1024, 512, 0, stream>>>(xbb, mwb, rw, partials);
  }
  {
    int grid = (OUT_ELEMS + 255) / 256;
    klindt_reduce_kernel<<<grid, 256, 0, stream>>>(partials, out);
  }
}

// Round 10
// 247.906 us; speedup vs baseline: 3.0834x; 1.2069x over previous
//
#include <hip/hip_runtime.h>

typedef unsigned short ushort_t;
typedef unsigned int uint_t;
typedef __attribute__((ext_vector_type(8))) short bf16x8;
typedef __attribute__((ext_vector_type(4))) float f32x4;

#define C_DIM 64
#define P_DIM 1296
#define N_DIM 2000
#define B_DIM 256
#define K_DIM (C_DIM * P_DIM)               // 82944
#define XB_ELEMS (B_DIM * K_DIM)            // 21233664
#define XB_ELEMS_PAD (XB_ELEMS + 256)       // 21233920
#define XB_BYTES ((size_t)XB_ELEMS_PAD * 2) // 42467840
#define SLICES 32
#define OUT_ELEMS (B_DIM * N_DIM)           // 512000
#define NSTEP 82                            // 2 channels x 41 BK=32 steps

static __device__ __forceinline__ ushort_t f2bf(float f) {
  unsigned u = __builtin_bit_cast(unsigned, f);
  u += 0x7fffu + ((u >> 16) & 1u);
  return (ushort_t)(u >> 16);
}

// ---------------- x (fp32) -> Xb (bf16) with zeroed pad tail ----------------
__global__ void klindt_cvt_kernel(const float4* __restrict__ x,
                                  unsigned long long* __restrict__ xb) {
  int idx = blockIdx.x * 256 + threadIdx.x;
  if (idx >= XB_ELEMS_PAD / 4) return;
  unsigned long long r = 0ull;
  if (idx < XB_ELEMS / 4) {
    float4 v = x[idx];
    r = (unsigned long long)f2bf(v.x) | ((unsigned long long)f2bf(v.y) << 16) |
        ((unsigned long long)f2bf(v.z) << 32) |
        ((unsigned long long)f2bf(v.w) << 48);
  }
  xb[idx] = r;
}

// ---------------- main GEMM: partials[slice][b][n] ----------------
// H11: B (mw stream) goes global -> registers -> MFMA B-fragment directly.
// No sB LDS, no pack/ds_write on the critical path, and the barrier guards
// ONLY the L2-resident A staging (vmcnt(10) = the 2 in-flight A-loads; the
// 8 B-loads always stay in flight). Wave tiling 1M x 8N: each of 8 waves owns
// 16 n-cols x all 256 m (16 MFMA/step, acc[16]) so B is loaded exactly once
// per block. BM=256 keeps mw read-once chip-wide; A triple-buffered in LDS.
__global__ void __launch_bounds__(512, 4) klindt_gemm_kernel(
    const char* __restrict__ xbb, const char* __restrict__ mwb,
    const float* __restrict__ rw, float* __restrict__ partials) {
  __shared__ ushort_t sA[3][8192];  // 3 x [256 m][32 k] bf16, 64B rows, XOR-swz

  const int tid = threadIdx.x;
  const int lane = tid & 63;
  const int wid = tid >> 6;  // 0..7 = n-wave
  const int r15 = lane & 15, g4 = lane >> 4;
  const int bid = blockIdx.x;
  const int slice = (bid & 7) + 8 * ((bid >> 3) & 3);  // 0..31, XCD-pinned
  const int n0 = (bid >> 5) * 128;                     // 16 n-tiles
  const int c0 = slice * 2;

  f32x4 acc[16];
#pragma unroll
  for (int i = 0; i < 16; ++i) {
    acc[i][0] = 0.f; acc[i][1] = 0.f; acc[i][2] = 0.f; acc[i][3] = 0.f;
  }

  // ---- A staging: linear LDS dest, inverse-swizzled global src (rule #21) --
  uint_t a_gbase[2]; int a_doff[2];
#pragma unroll
  for (int it = 0; it < 2; ++it) {
    int chunk = it * 512 + tid;
    int row = chunk >> 2, t4 = chunk & 3;
    int ss = t4 ^ ((row >> 1) & 3);
    a_gbase[it] = (uint_t)(row * K_DIM + ss * 8) * 2u;  // byte off into xb
    a_doff[it] = chunk * 8;                             // elem off into sA
  }

  // ---- B constants: lane = n-column (wave-exclusive), lane-group = k-rows --
  const int nidx = n0 + wid * 16 + r15;
  const bool okn = nidx < N_DIM;
  const uint_t nb4 = (uint_t)(okn ? nidx : (N_DIM - 1)) * 4u;
  const float rvl = okn ? rw[c0 * N_DIM + nidx] : 0.f;
  const float rvh = okn ? rw[(c0 + 1) * N_DIM + nidx] : 0.f;
  const uint_t pg = (uint_t)(g4 * 8);  // per-lane-group p offset

  // ---- A fragment read offset (swizzle-consistent; full 256-m per wave) ----
  const int swz = g4 ^ ((r15 >> 1) & 3);
  const int aoffbase = r15 * 32 + swz * 8;

  float mv[8];   // B register bank (depth-1 prefetch: load at s for s+1)
  bf16x8 bfr;    // current step's B fragment

  auto issueA = [&](int buf, int t) {
    int half = (t >= 41) ? 1 : 0;
    int sp = t - 41 * half;
    uint_t kb = ((uint_t)(c0 + half) * (uint_t)P_DIM + (uint_t)sp * 32u) * 2u;
#pragma unroll
    for (int it = 0; it < 2; ++it) {
      const char* g = xbb + (a_gbase[it] + kb);
      __builtin_amdgcn_global_load_lds(
          (const __attribute__((address_space(1))) unsigned int*)g,
          (__attribute__((address_space(3))) unsigned int*)(&sA[buf][a_doff[it]]),
          16, 0, 0);
    }
  };
  auto issueB = [&](int t) {
    int half = (t >= 41) ? 1 : 0;
    int sp = t - 41 * half;
    uint_t p0 = (uint_t)sp * 32u + pg;
    if (p0 > 1288u) p0 = 1288u;  // tail clamp (in-bounds; zeroed at cvt)
    const char* bp = mwb + (p0 * 512000u + (uint_t)(c0 + half) * 8000u + nb4);
#pragma unroll
    for (int j = 0; j < 8; ++j)
      mv[j] = *(const float*)(bp + (uint_t)j * 512000u);
  };
  auto cvtB = [&](int t) {
    float rv = (t >= 41) ? rvh : rvl;
    if ((t == 40 || t == 81) && g4 >= 2) rv = 0.f;  // k>=16 invalid at tails
#pragma unroll
    for (int j = 0; j < 8; ++j) bfr[j] = (short)f2bf(mv[j] * rv);
  };
  auto computeStep = [&](int buf) {
    __builtin_amdgcn_s_setprio(1);
#pragma unroll
    for (int fm = 0; fm < 16; ++fm) {
      bf16x8 afr = *(const bf16x8*)(&sA[buf][aoffbase + fm * 512]);
      acc[fm] = __builtin_amdgcn_mfma_f32_16x16x32_bf16(afr, bfr, acc[fm],
                                                        0, 0, 0);
    }
    __builtin_amdgcn_s_setprio(0);
  };

  // ---- prologue: B(0) + A(0) + A(1); drain B(0),A(0); keep A(1) in flight --
  issueB(0);
  issueA(0, 0);
  issueA(1, 1);
  asm volatile("s_waitcnt vmcnt(2) lgkmcnt(0)" ::: "memory");
  __builtin_amdgcn_sched_barrier(0);
  __builtin_amdgcn_s_barrier();
  __builtin_amdgcn_sched_barrier(0);

  // ---- main loop: bodies 0..79 ----
  // Steady state at barrier: outstanding = A(s+1)[2] + B(s+1)[8] + A(s+2)[2];
  // vmcnt(10) drains exactly A(s+1). The mw stream never drains.
  int cur = 0;
  for (int s = 0; s < 80; ++s) {
    int bufW = (cur >= 1) ? cur - 1 : 2;  // (cur+2)%3
    cvtB(s);           // compiler waits only B(s)'s 8 loads
    issueB(s + 1);     // reload bank for next step
    issueA(bufW, s + 2);
    computeStep(cur);  // 16 ds_read_b128 + 16 MFMA
    asm volatile("s_waitcnt vmcnt(10) lgkmcnt(0)" ::: "memory");
    __builtin_amdgcn_sched_barrier(0);
    __builtin_amdgcn_s_barrier();
    __builtin_amdgcn_sched_barrier(0);
    cur = (cur == 2) ? 0 : cur + 1;
  }
  // ---- body 80 (no A prefetch; drain A(81), keep B(81) in flight) ----
  cvtB(80);
  issueB(81);
  computeStep(2);  // 80 % 3
  asm volatile("s_waitcnt vmcnt(8) lgkmcnt(0)" ::: "memory");
  __builtin_amdgcn_sched_barrier(0);
  __builtin_amdgcn_s_barrier();
  __builtin_amdgcn_sched_barrier(0);
  // ---- body 81 ----
  cvtB(81);
  computeStep(0);  // 81 % 3

  // ---- epilogue: fp32 partials for this K-slice ----
  float* pb = partials + (size_t)slice * OUT_ELEMS;
  if (okn) {
#pragma unroll
    for (int fm = 0; fm < 16; ++fm) {
#pragma unroll
      for (int rr = 0; rr < 4; ++rr) {
        int m = fm * 16 + g4 * 4 + rr;
        pb[m * N_DIM + nidx] = acc[fm][rr];
      }
    }
  }
}

// ---------------- deterministic split-K reduction ----------------
__global__ void klindt_reduce_kernel(const float* __restrict__ part,
                                     float* __restrict__ out) {
  int i = blockIdx.x * 256 + threadIdx.x;
  if (i < OUT_ELEMS) {
    float s = 0.f;
#pragma unroll
    for (int k = 0; k < SLICES; ++k) s += part[(size_t)k * OUT_ELEMS + i];
    out[i] = s;
  }
}

extern "C" void kernel_launch(void* const* d_in, const int* in_sizes, int n_in,
                              void* d_out, int out_size, void* d_ws,
                              size_t ws_size, hipStream_t stream) {
  (void)in_sizes; (void)n_in; (void)out_size; (void)ws_size;
  const float* x = (const float*)d_in[0];
  const char* mwb = (const char*)d_in[1];
  const float* rw = (const float*)d_in[2];
  float* out = (float*)d_out;

  char* xbb = (char*)d_ws;
  float* partials = (float*)((char*)d_ws + XB_BYTES);

  {
    int nvec = XB_ELEMS_PAD / 4;
    int grid = (nvec + 255) / 256;
    klindt_cvt_kernel<<<grid, 256, 0, stream>>>((const float4*)x,
                                                (unsigned long long*)xbb);
  }
  {
    klindt_gemm_kernel<<<512, 512, 0, stream>>>(xbb, mwb, rw, partials);
  }
  {
    int grid = (OUT_ELEMS + 255) / 256;
    klindt_reduce_kernel<<<grid, 256, 0, stream>>>(partials, out);
  }
}

// Round 11
// 244.835 us; speedup vs baseline: 3.1221x; 1.0125x over previous
//
#include <hip/hip_runtime.h>

typedef unsigned short ushort_t;
typedef unsigned int uint_t;
typedef __attribute__((ext_vector_type(8))) short bf16x8;
typedef __attribute__((ext_vector_type(4))) float f32x4;

#define C_DIM 64
#define P_DIM 1296
#define N_DIM 2000
#define B_DIM 256
#define K_DIM (C_DIM * P_DIM)               // 82944
#define XB_ELEMS (B_DIM * K_DIM)            // 21233664
#define XB_ELEMS_PAD (XB_ELEMS + 256)       // 21233920
#define XB_BYTES ((size_t)XB_ELEMS_PAD * 2) // 42467840
#define SLICES 32
#define OUT_ELEMS (B_DIM * N_DIM)           // 512000
#define NSTEP 42                            // 2 channels x 21 BK=64 steps

static __device__ __forceinline__ ushort_t f2bf(float f) {
  unsigned u = __builtin_bit_cast(unsigned, f);
  u += 0x7fffu + ((u >> 16) & 1u);
  return (ushort_t)(u >> 16);
}

// ---------------- x (fp32) -> Xb (bf16) with zeroed pad tail ----------------
__global__ void klindt_cvt_kernel(const float4* __restrict__ x,
                                  unsigned long long* __restrict__ xb) {
  int idx = blockIdx.x * 256 + threadIdx.x;
  if (idx >= XB_ELEMS_PAD / 4) return;
  unsigned long long r = 0ull;
  if (idx < XB_ELEMS / 4) {
    float4 v = x[idx];
    r = (unsigned long long)f2bf(v.x) | ((unsigned long long)f2bf(v.y) << 16) |
        ((unsigned long long)f2bf(v.z) << 32) |
        ((unsigned long long)f2bf(v.w) << 48);
  }
  xb[idx] = r;
}

// ---------------- main GEMM: partials[slice][b][n] ----------------
// H12: BK=64 — halve the barrier count, double mw bytes per step, so the
// fixed per-step serial cost (the measured ~3kcyc/step that no schedule
// variant removed) is amortized 2x. Structure = R10 (register-direct B,
// 1Mx8N waves, A LDS-staged from L2-pinned xb, XCD-pinned slices).
// sA: [2][256 m][64 k] bf16 rows of 8x16B slots, slot XOR-swizzled by m&7.
// FIFO: A issued before B each body -> vmcnt(16) drains A only; the mw
// stream (16 loads/thread) always stays in flight across barriers.
__global__ void __launch_bounds__(512, 4) klindt_gemm_kernel(
    const char* __restrict__ xbb, const char* __restrict__ mwb,
    const float* __restrict__ rw, float* __restrict__ partials) {
  __shared__ ushort_t sA[2][16384];  // 2 x 32 KB

  const int tid = threadIdx.x;
  const int lane = tid & 63;
  const int wid = tid >> 6;  // 0..7 = n-wave
  const int r15 = lane & 15, g4 = lane >> 4;
  const int bid = blockIdx.x;
  const int slice = (bid & 7) + 8 * ((bid >> 3) & 3);  // 0..31, XCD-pinned
  const int n0 = (bid >> 5) * 128;                     // 16 n-tiles
  const int c0 = slice * 2;

  f32x4 acc[16];
#pragma unroll
  for (int i = 0; i < 16; ++i) {
    acc[i][0] = 0.f; acc[i][1] = 0.f; acc[i][2] = 0.f; acc[i][3] = 0.f;
  }

  // ---- A staging: linear LDS dest, inverse-swizzled global src (rule #21) --
  // chunk = it*512+tid (it 0..3): row = chunk>>3, slot = chunk&7,
  // src slot ss = slot ^ (row&7). 4 x global_load_lds(16B) per thread/step.
  uint_t a_gbase[4]; int a_doff[4];
#pragma unroll
  for (int it = 0; it < 4; ++it) {
    int chunk = it * 512 + tid;
    int row = chunk >> 3, sl = chunk & 7;
    int ss = sl ^ (row & 7);
    a_gbase[it] = (uint_t)(row * K_DIM + ss * 8) * 2u;  // byte off into xb
    a_doff[it] = chunk * 8;                             // elem off into sA
  }

  // ---- B constants: lane = n-column (wave-exclusive), g4 = k-group of 8 ----
  const int nidx = n0 + wid * 16 + r15;
  const bool okn = nidx < N_DIM;
  const uint_t nb4 = (uint_t)(okn ? nidx : (N_DIM - 1)) * 4u;
  const float rvl = okn ? rw[c0 * N_DIM + nidx] : 0.f;
  const float rvh = okn ? rw[(c0 + 1) * N_DIM + nidx] : 0.f;
  const uint_t pg = (uint_t)(g4 * 8);  // per-lane-group p offset

  // ---- A fragment read offsets (swizzle-consistent) ----
  // row m = r15 + fm*16 (m&7 == r15&7), slot(kh) = (g4+4kh) ^ (r15&7)
  const int swz7 = r15 & 7;
  const int aoff0 = r15 * 128 + ((g4 ^ swz7) & 7) * 16;        // bytes, kh=0
  const int aoff1 = r15 * 128 + (((g4 + 4) ^ swz7) & 7) * 16;  // bytes, kh=1

  float mvE[16], mvO[16];  // B register double-buffer (static parity)

  auto issueA = [&](int buf, int t) {
    int half = (t >= 21) ? 1 : 0;
    int sp = t - 21 * half;
    uint_t kb = ((uint_t)(c0 + half) * (uint_t)P_DIM + (uint_t)sp * 64u) * 2u;
#pragma unroll
    for (int it = 0; it < 4; ++it) {
      const char* g = xbb + (a_gbase[it] + kb);
      __builtin_amdgcn_global_load_lds(
          (const __attribute__((address_space(1))) unsigned int*)g,
          (__attribute__((address_space(3))) unsigned int*)(&sA[buf][a_doff[it]]),
          16, 0, 0);
    }
  };

#define ISSUE_B(MV, T)                                                        \
  do {                                                                        \
    int half_ = ((T) >= 21) ? 1 : 0;                                          \
    int sp_ = (T)-21 * half_;                                                 \
    uint_t pa_ = (uint_t)(sp_ * 64) + pg;                                     \
    uint_t pb_ = pa_ + 32u;                                                   \
    if (pa_ > 1288u) pa_ = 1288u; /* tail clamp; zeroed via rv at cvt */      \
    if (pb_ > 1288u) pb_ = 1288u;                                             \
    uint_t cb_ = (uint_t)(c0 + half_) * 8000u + nb4;                          \
    const char* ba_ = mwb + (pa_ * 512000u + cb_);                            \
    const char* bb_ = mwb + (pb_ * 512000u + cb_);                            \
    _Pragma("unroll") for (int j_ = 0; j_ < 8; ++j_)                          \
        MV[j_] = *(const float*)(ba_ + (uint_t)j_ * 512000u);                 \
    _Pragma("unroll") for (int j_ = 0; j_ < 8; ++j_)                          \
        MV[8 + j_] = *(const float*)(bb_ + (uint_t)j_ * 512000u);             \
  } while (0)

#define CVT_COMPUTE(BUF, MV, T)                                               \
  do {                                                                        \
    int half_ = ((T) >= 21) ? 1 : 0;                                          \
    int sp_ = (T)-21 * half_;                                                 \
    float rv_ = half_ ? rvh : rvl;                                            \
    float rva_ = (sp_ < 20 || g4 < 2) ? rv_ : 0.f;                            \
    float rvb_ = (sp_ < 20) ? rv_ : 0.f;                                      \
    bf16x8 b0_, b1_;                                                          \
    _Pragma("unroll") for (int j_ = 0; j_ < 8; ++j_) {                        \
      b0_[j_] = (short)f2bf(MV[j_] * rva_);                                   \
      b1_[j_] = (short)f2bf(MV[8 + j_] * rvb_);                               \
    }                                                                         \
    __builtin_amdgcn_s_setprio(1);                                            \
    _Pragma("unroll") for (int fm_ = 0; fm_ < 16; ++fm_) {                    \
      bf16x8 a0_ = *(const bf16x8*)((const char*)&sA[BUF][0] +                \
                                    (aoff0 + fm_ * 2048));                    \
      acc[fm_] = __builtin_amdgcn_mfma_f32_16x16x32_bf16(a0_, b0_, acc[fm_],  \
                                                         0, 0, 0);            \
      bf16x8 a1_ = *(const bf16x8*)((const char*)&sA[BUF][0] +                \
                                    (aoff1 + fm_ * 2048));                    \
      acc[fm_] = __builtin_amdgcn_mfma_f32_16x16x32_bf16(a1_, b1_, acc[fm_],  \
                                                         0, 0, 0);            \
    }                                                                         \
    __builtin_amdgcn_s_setprio(0);                                            \
  } while (0)

  // ---- prologue: A(0) then B(0); drain A(0), keep B(0) in flight ----
  issueA(0, 0);
  ISSUE_B(mvE, 0);
  asm volatile("s_waitcnt vmcnt(16) lgkmcnt(0)" ::: "memory");
  __builtin_amdgcn_sched_barrier(0);
  __builtin_amdgcn_s_barrier();
  __builtin_amdgcn_sched_barrier(0);

#define BODY(S, MV_CUR, MV_NEXT)                                              \
  {                                                                           \
    issueA(((S) + 1) & 1, (S) + 1); /* 4 loads, oldest this body */           \
    ISSUE_B(MV_NEXT, (S) + 1);      /* 16 loads, ride across barrier */       \
    CVT_COMPUTE((S)&1, MV_CUR, S);  /* cvt waits only MV_CUR (oldest) */      \
    asm volatile("s_waitcnt vmcnt(16) lgkmcnt(0)" ::: "memory");              \
    __builtin_amdgcn_sched_barrier(0);                                        \
    __builtin_amdgcn_s_barrier();                                             \
    __builtin_amdgcn_sched_barrier(0);                                        \
  }

  // ---- main loop: bodies 0..39 ----
  for (int s = 0; s < 40; s += 2) {
    BODY(s, mvE, mvO);
    BODY(s + 1, mvO, mvE);
  }
  // ---- body 40 (prefetch 41) ----
  BODY(40, mvE, mvO);
  // ---- body 41 (no prefetch) ----
  CVT_COMPUTE(1, mvO, 41);

  // ---- epilogue: fp32 partials for this K-slice ----
  float* pb = partials + (size_t)slice * OUT_ELEMS;
  if (okn) {
#pragma unroll
    for (int fm = 0; fm < 16; ++fm) {
#pragma unroll
      for (int rr = 0; rr < 4; ++rr) {
        int m = fm * 16 + g4 * 4 + rr;
        pb[m * N_DIM + nidx] = acc[fm][rr];
      }
    }
  }
#undef BODY
#undef ISSUE_B
#undef CVT_COMPUTE
}

// ---------------- deterministic split-K reduction ----------------
__global__ void klindt_reduce_kernel(const float* __restrict__ part,
                                     float* __restrict__ out) {
  int i = blockIdx.x * 256 + threadIdx.x;
  if (i < OUT_ELEMS) {
    float s = 0.f;
#pragma unroll
    for (int k = 0; k < SLICES; ++k) s += part[(size_t)k * OUT_ELEMS + i];
    out[i] = s;
  }
}

extern "C" void kernel_launch(void* const* d_in, const int* in_sizes, int n_in,
                              void* d_out, int out_size, void* d_ws,
                              size_t ws_size, hipStream_t stream) {
  (void)in_sizes; (void)n_in; (void)out_size; (void)ws_size;
  const float* x = (const float*)d_in[0];
  const char* mwb = (const char*)d_in[1];
  const float* rw = (const float*)d_in[2];
  float* out = (float*)d_out;

  char* xbb = (char*)d_ws;
  float* partials = (float*)((char*)d_ws + XB_BYTES);

  {
    int nvec = XB_ELEMS_PAD / 4;
    int grid = (nvec + 255) / 256;
    klindt_cvt_kernel<<<grid, 256, 0, stream>>>((const float4*)x,
                                                (unsigned long long*)xbb);
  }
  {
    klindt_gemm_kernel<<<512, 512, 0, stream>>>(xbb, mwb, rw, partials);
  }
  {
    int grid = (OUT_ELEMS + 255) / 256;
    klindt_reduce_kernel<<<grid, 256, 0, stream>>>(partials, out);
  }
}